// Round 16
// baseline (146.425 us; speedup 1.0000x reference)
//
#include <hip/hip_runtime.h>
#include <hip/hip_bf16.h>
#include <math.h>

#define DDIM 7168
#define NEXP 256
#define NGRP 8
#define TOPKG 4
#define TOPK 8
#define ROUTE_SCALE 2.5f

#define BM 64
#define BN 256
#define BK 32
#define KSPLIT 4
#define KPER (DDIM / KSPLIT)        // 1792
#define NSTEP (KPER / BK)           // 56
#define NKTILE (DDIM / BK)          // 224
#define BT_ELEMS (NEXP * BK * 2)    // 16384 shorts = 32 KB per k-tile (hi 16KB + lo 16KB)
#define BH_ELEMS (NEXP * BK)        // 8192 shorts = 16 KB hi-half
#define AT_FLOATS (BM * BK)         // 2048 f32 = 8 KB A-tile

typedef __attribute__((ext_vector_type(8))) short bf16x8;
typedef __attribute__((ext_vector_type(4))) float f32x4;
typedef unsigned int u32;
typedef unsigned short ushort_t;

static __device__ __forceinline__ ushort_t bf16_rne(float f) {
    u32 b = __float_as_uint(f);
    u32 r = (b + 0x7fffu + ((b >> 16) & 1u)) >> 16;
    return (ushort_t)r;
}
static __device__ __forceinline__ float bf16_to_f32(ushort_t h) {
    return __uint_as_float(((u32)h) << 16);
}
// hi = bf16(f) via HW cvt; lo = bf16(f - hi)
static __device__ __forceinline__ void split_elem(float f, short& h, short& l) {
    union { __hip_bfloat16 b; short s; } cv;
    cv.b = __float2bfloat16(f);
    h = cv.s;
    float hf = __uint_as_float(((u32)(ushort_t)cv.s) << 16);
    cv.b = __float2bfloat16(f - hf);
    l = cv.s;
}

// ---------------------------------------------------------------------------
// Kernel 0: split w into hi/lo bf16, fragment-linear per BK=32 k-tile.
// Tile (32 KB): [pass(2)][fn(16)][lane(64)][8 bf16]  (R3/R13-proven)
// hi occupies the first 16 KB (staged to LDS); lo the second (read from L2).
// ---------------------------------------------------------------------------
__global__ __launch_bounds__(256) void wsplit_kernel(const float* __restrict__ w,
                                                     short* __restrict__ wsp)
{
    const int kt = blockIdx.x;      // 0..223
    const int e  = threadIdx.x;     // expert 0..255
    const float* wp = w + (size_t)e * DDIM + (size_t)kt * BK;
    short* tb = wsp + (size_t)kt * BT_ELEMS;
    const int fn = e >> 4, er = e & 15;
    #pragma unroll
    for (int jg = 0; jg < 4; jg++) {
        float f[8];
        *(float4*)&f[0] = *(const float4*)(wp + jg * 8);
        *(float4*)&f[4] = *(const float4*)(wp + jg * 8 + 4);
        ushort_t h[8], l[8];
        #pragma unroll
        for (int j = 0; j < 8; j++) {
            h[j] = bf16_rne(f[j]);
            l[j] = bf16_rne(f[j] - bf16_to_f32(h[j]));
        }
        const int lane = jg * 16 + er;
        *(uint4*)(tb + ((size_t)(0 * 16 + fn) * 64 + lane) * 8) = *(uint4*)h;
        *(uint4*)(tb + ((size_t)(1 * 16 + fn) * 64 + lane) * 8) = *(uint4*)l;
    }
}

// ---------------------------------------------------------------------------
// Kernel 1: split-precision bf16 MFMA GEMM — R13 geometry (the champion:
// 16 waves/CU) + counted-vmcnt 3-buffer pipeline + B-lo direct from L2.
//  * R13/R14/R15 decomposition: waves/CU dominates (16 -> 106us, 8 -> 146+).
//    Keep BM=64/BN=256/BK=32, 512 thr (8 waves of 32x64), 2 blk/CU.
//  * LDS diet: only B-hi staged (16KB) + A (8KB); B-lo read per-wave from L2
//    (fragment-linear -> coalesced dwordx4; 1.84MB w-slice per XCD stays hot).
//    3 buffers = 72KB -> still 2 blocks/CU.
//  * Counted pipeline (T4): per step issue Blo(st)[4 vmem] THEN grp(st+2)
//    [2 Bhi-glds + 1 A-glds]. Compiler's auto-wait before the Blo-consuming
//    pass = vmcnt(3) (leaves grp(st+2) in flight); top-of-step wait =
//    vmcnt(3) retires exactly grp(st). NO vmcnt(0) in the main loop.
//    Verified uniform over prologue (st=0: [grp0 3, grp1 3] -> vmcnt(3)
//    retires grp0) and tail. WAR: buf(st+2)%3 last ds_read at st-1, retired
//    via lgkmcnt(0) before barrier(st). sched_barrier(0) pins Blo-before-DMA.
//  * A path verbatim R13: coalesced swizzled source, linear LDS dest,
//    XOR-swizzled read (round-trip proven).
// grid = 128 mt x 4 ksp = 512; XCD: bid&7 -> ksp, mt interleaved (R13 map).
// ---------------------------------------------------------------------------
__global__ __launch_bounds__(512, 4) void gemm_split_kernel(
    const float* __restrict__ x, const short* __restrict__ wsp,
    float* __restrict__ part, int Btok)
{
    __shared__ short Blds[3][BH_ELEMS];    // 3 x 16 KB (B-hi only)
    __shared__ float Alds[3][AT_FLOATS];   // 3 x  8 KB  (total 72 KB)

    const int bid  = blockIdx.x;
    const int xcd  = bid & 7;
    const int ksp  = xcd & 3;
    const int mt   = (bid >> 3) * 2 + (xcd >> 2);   // 0..127, bijective
    const int m0   = mt * BM;
    const int kbase = ksp * KPER;
    const int t    = threadIdx.x;
    const int wid  = t >> 6, lane = t & 63;
    const int wm   = wid >> 2, wn = wid & 3;
    const int lr   = lane & 15, lg = lane >> 4;

    const short* wt0 = wsp + (size_t)(ksp * NSTEP) * BT_ELEMS;

    // A staging source (pre-swizzled, coalesced; R13-proven): 1 instr/wave/step
    const int arow  = wid * 8 + (lane >> 3);                  // 0..63
    const int akoff = 4 * ((lane & 7) ^ ((lane >> 3) & 7));   // float offset
    const float* asrc0 = x + (size_t)(m0 + arow) * DDIM + kbase + akoff;
    const int adst_off = wid * 1024 + lane * 16;              // linear LDS bytes

#define STAGE_GRP(stp, bptr, aptr) do {                                                    \
        const short* gt_ = wt0 + (size_t)(stp) * BT_ELEMS;                                 \
        _Pragma("unroll")                                                                  \
        for (int i_ = 0; i_ < 2; i_++) {                                                   \
            const int off_ = wid * 2048 + i_ * 1024;                                       \
            __builtin_amdgcn_global_load_lds(                                              \
                (const __attribute__((address_space(1))) u32*)((const char*)gt_ + off_ + lane * 16), \
                (__attribute__((address_space(3))) u32*)((char*)(bptr) + off_),            \
                16, 0, 0);                                                                 \
        }                                                                                  \
        __builtin_amdgcn_global_load_lds(                                                  \
            (const __attribute__((address_space(1))) u32*)(asrc0 + (size_t)(stp) * BK),    \
            (__attribute__((address_space(3))) u32*)((char*)(aptr) + adst_off),            \
            16, 0, 0);                                                                     \
    } while (0)

    f32x4 acc[2][4];
    #pragma unroll
    for (int i = 0; i < 2; i++)
        #pragma unroll
        for (int j = 0; j < 4; j++) acc[i][j] = (f32x4){0.f, 0.f, 0.f, 0.f};

    // rotating buffers: _r = step st, _1 = st+1, _2 = dest for st+2
    short* pB_r = &Blds[0][0]; short* pB_1 = &Blds[1][0]; short* pB_2 = &Blds[2][0];
    float* pA_r = &Alds[0][0]; float* pA_1 = &Alds[1][0]; float* pA_2 = &Alds[2][0];

    // ---- prologue: grp(0), grp(1) (3 DMA each) ----
    STAGE_GRP(0, pB_r, pA_r);
    STAGE_GRP(1, pB_1, pA_1);

    for (int st = 0; st < NSTEP; st++) {
        // retire exactly grp(st) (outstanding: grp(st+1)[3] after prior waits)
        asm volatile("s_waitcnt vmcnt(3)" ::: "memory");
        asm volatile("s_waitcnt lgkmcnt(0)" ::: "memory");
        __builtin_amdgcn_s_barrier();

        // ---- B-lo fragment loads from L2 (MUST precede the DMA issue so the
        //      compiler's auto-wait for them is a counted vmcnt, not 0) ----
        const short* blo = wt0 + (size_t)st * BT_ELEMS + BH_ELEMS;
        bf16x8 blv[4];
        #pragma unroll
        for (int fn = 0; fn < 4; fn++)
            blv[fn] = *(const bf16x8*)&blo[((size_t)(wn * 4 + fn) * 64 + lane) * 8];
        __builtin_amdgcn_sched_barrier(0);   // pin: Blo issued before grp DMAs

        // ---- issue grp(st+2) into the buffer read at step st-1 ----
        if (st + 2 < NSTEP) STAGE_GRP(st + 2, pB_2, pA_2);

        // ---- A fragments from LDS (swizzled read) + hi/lo convert ----
        const char* ab = (const char*)pA_r;
        bf16x8 ah[2], al[2];
        #pragma unroll
        for (int fm = 0; fm < 2; fm++) {
            const int row = wm * 32 + fm * 16 + lr;
            const int rb  = row * 128;
            const int sw  = (lr & 7) << 4;
            float fr[8];
            *(float4*)&fr[0] = *(const float4*)(ab + rb + ((lg * 32) ^ sw));
            *(float4*)&fr[4] = *(const float4*)(ab + rb + ((lg * 32 + 16) ^ sw));
            union { bf16x8 v; short s[8]; } H, L;
            #pragma unroll
            for (int j = 0; j < 8; j++)
                split_elem(fr[j], H.s[j], L.s[j]);
            ah[fm] = H.v;
            al[fm] = L.v;
        }

        // ---- B-hi fragments from LDS (lane-linear) ----
        bf16x8 bhv[4];
        #pragma unroll
        for (int fn = 0; fn < 4; fn++)
            bhv[fn] = *(const bf16x8*)&pB_r[((size_t)(wn * 4 + fn) * 64 + lane) * 8];

        // ---- MFMA pass-major; Blo-consuming pass LAST (max load lead) ----
        #pragma unroll
        for (int fn = 0; fn < 4; fn++)
            #pragma unroll
            for (int fm = 0; fm < 2; fm++)
                acc[fm][fn] = __builtin_amdgcn_mfma_f32_16x16x32_bf16(ah[fm], bhv[fn], acc[fm][fn], 0, 0, 0);
        #pragma unroll
        for (int fn = 0; fn < 4; fn++)
            #pragma unroll
            for (int fm = 0; fm < 2; fm++)
                acc[fm][fn] = __builtin_amdgcn_mfma_f32_16x16x32_bf16(al[fm], bhv[fn], acc[fm][fn], 0, 0, 0);
        #pragma unroll
        for (int fn = 0; fn < 4; fn++)
            #pragma unroll
            for (int fm = 0; fm < 2; fm++)
                acc[fm][fn] = __builtin_amdgcn_mfma_f32_16x16x32_bf16(ah[fm], blv[fn], acc[fm][fn], 0, 0, 0);

        // ---- rotate buffers ----
        { short* tb_ = pB_r; pB_r = pB_1; pB_1 = pB_2; pB_2 = tb_; }
        { float* ta_ = pA_r; pA_r = pA_1; pA_1 = pA_2; pA_2 = ta_; }
    }
#undef STAGE_GRP

    // ---- epilogue: fp32 partials (C/D map: col=lane&15, row=(lane>>4)*4+reg) ----
    float* pp = part + (size_t)ksp * (size_t)Btok * NEXP;
    #pragma unroll
    for (int fm = 0; fm < 2; fm++) {
        const int row0 = m0 + wm * 32 + fm * 16 + lg * 4;
        #pragma unroll
        for (int fn = 0; fn < 4; fn++) {
            const int col = wn * 64 + fn * 16 + lr;
            #pragma unroll
            for (int rr = 0; rr < 4; rr++)
                pp[(size_t)(row0 + rr) * NEXP + col] = acc[fm][fn][rr];
        }
    }
}

// ---------------------------------------------------------------------------
// Kernel 2: reduce split-K partials + sigmoid + full gating, one wave per row.
// (unchanged — proven)
// ---------------------------------------------------------------------------
__global__ __launch_bounds__(256) void gate_kernel(
    const float* __restrict__ part, const float* __restrict__ bias,
    float* __restrict__ out_w, float* __restrict__ out_i, int B)
{
    const int lane = threadIdx.x & 63;
    const int wid  = threadIdx.x >> 6;
    const int row  = blockIdx.x * 4 + wid;
    if (row >= B) return;

    const size_t plane = (size_t)B * NEXP;
    const float* pr = part + (size_t)row * NEXP + lane * 4;
    float4 v0 = *(const float4*)(pr);
    float4 v1 = *(const float4*)(pr + plane);
    float4 v2 = *(const float4*)(pr + 2 * plane);
    float4 v3 = *(const float4*)(pr + 3 * plane);
    float sc[4] = { v0.x + v1.x + v2.x + v3.x,
                    v0.y + v1.y + v2.y + v3.y,
                    v0.z + v1.z + v2.z + v3.z,
                    v0.w + v1.w + v2.w + v3.w };
    float4 bv = *(const float4*)(bias + lane * 4);
    const float bb[4] = { bv.x, bv.y, bv.z, bv.w };

    float so[4], sb[4];
    #pragma unroll
    for (int j = 0; j < 4; j++) {
        so[j] = 1.0f / (1.0f + expf(-sc[j]));
        sb[j] = so[j] + bb[j];
    }

    float m1 = sb[0], m2 = -INFINITY;
    #pragma unroll
    for (int j = 1; j < 4; j++) {
        if (sb[j] > m1)      { m2 = m1; m1 = sb[j]; }
        else if (sb[j] > m2) { m2 = sb[j]; }
    }
    #pragma unroll
    for (int m = 1; m <= 4; m <<= 1) {
        float o1 = __shfl_xor(m1, m);
        float o2 = __shfl_xor(m2, m);
        float hi = fmaxf(m1, o1);
        float lo = fminf(m1, o1);
        m1 = hi;
        m2 = fmaxf(lo, fmaxf(m2, o2));
    }
    float gscore = m1 + m2;
    int g = lane >> 3;

    float gs[NGRP];
    #pragma unroll
    for (int gg = 0; gg < NGRP; gg++) gs[gg] = __shfl(gscore, gg * 8);
    int rank = 0;
    #pragma unroll
    for (int gg = 0; gg < NGRP; gg++) {
        if (gg == g) continue;
        if (gs[gg] > gs[g] || (gs[gg] == gs[g] && gg < g)) rank++;
    }
    const bool selg = (rank < TOPKG);
    float mv[4];
    #pragma unroll
    for (int j = 0; j < 4; j++) mv[j] = selg ? sb[j] : -INFINITY;

    float wsel[TOPK];
    int   isel[TOPK];
    float wsum = 0.f;
    #pragma unroll
    for (int it = 0; it < TOPK; it++) {
        float v = mv[0]; int jj = 0;
        #pragma unroll
        for (int j = 1; j < 4; j++)
            if (mv[j] > v) { v = mv[j]; jj = j; }
        int gi = (lane << 2) | jj;
        #pragma unroll
        for (int m = 1; m < 64; m <<= 1) {
            float ov = __shfl_xor(v, m);
            int   oi = __shfl_xor(gi, m);
            if (ov > v || (ov == v && oi < gi)) { v = ov; gi = oi; }
        }
        int slot = gi & 3, src = gi >> 2;
        float cand = (slot == 0) ? so[0] : (slot == 1) ? so[1] : (slot == 2) ? so[2] : so[3];
        float sval = __shfl(cand, src);
        wsel[it] = sval; isel[it] = gi; wsum += sval;
        if (lane == src) mv[slot] = -INFINITY;
    }

    if (lane == 0) {
        float scl = ROUTE_SCALE / wsum;
        #pragma unroll
        for (int it = 0; it < TOPK; it++) {
            out_w[(size_t)row * TOPK + it] = wsel[it] * scl;
            out_i[(size_t)row * TOPK + it] = (float)isel[it];
        }
    }
}

extern "C" void kernel_launch(void* const* d_in, const int* in_sizes, int n_in,
                              void* d_out, int out_size, void* d_ws, size_t ws_size,
                              hipStream_t stream)
{
    const float* x    = (const float*)d_in[0];
    const float* w    = (const float*)d_in[1];
    const float* bias = (const float*)d_in[2];
    const int B = in_sizes[0] / DDIM;           // 8192

    // ws layout: [ part: 4 * B * 256 f32 = 32 MB ][ wsp: 224 tiles * 32 KB = 7.34 MB ]
    float* part = (float*)d_ws;
    short* wsp  = (short*)((char*)d_ws + (size_t)KSPLIT * B * NEXP * sizeof(float));

    float* out_w = (float*)d_out;
    float* out_i = out_w + (size_t)B * TOPK;

    hipLaunchKernelGGL(wsplit_kernel, dim3(NKTILE), dim3(256), 0, stream, w, wsp);
    hipLaunchKernelGGL(gemm_split_kernel, dim3((B / BM) * KSPLIT), dim3(512), 0, stream,
                       x, wsp, part, B);
    hipLaunchKernelGGL(gate_kernel, dim3((B + 3) / 4), dim3(256), 0, stream,
                       part, bias, out_w, out_i, B);
}